// Round 11
// baseline (117.691 us; speedup 1.0000x reference)
//
#include <hip/hip_runtime.h>

#define FF_N 4096
#define S64  0.015625f   // 1/64 per FWHT (total 1/4096)

// ============================================================================
// float2-packed (2 rows/thread) radix-16 FastFood. Digits: e = 256*d2+16*d1+d0.
// LDS = one float2[4096] buffer (32 KB) reused by all junctions.
// Pair-unit (float2-index) layouts, all bijective [0,4096), all conflict-free
// under the R8-validated rigid-group model (8-lane/quad for b128 writes,
// 16-lane/pair for b64 reads):
//  A-layout  (J1/J4: write all-d0, read all-d1):
//     aA(d1,d2,d0) = 256*d1 + 16*d2 + 2*((d0>>1)^(d1&7)) + (d0&1)
//     write quad = m^(c&7) distinct; read pair = 2((c>>1)^(j&7))+(c&1) bijective
//  P-layout  (J2/J5: write all-d1, read all-d2):
//     aP(d2,d1,d0) = 256*d2 + 32*(d1>>1) + 2*d0 + ((d1&1)^(d0>>3))
//     write quad = c&7 distinct (pack-swap by h=c>>3); read pair =
//     (2c + (T&1)^(c>>3)) bijective (c<8 evens+b, c>=8 evens+b^1)
//  W-layout  (gather source: write all-d2, random read):
//     aW(d2,d1,d0) = 512*(d2>>1) + 32*d1 + 2*(d0^((d2>>1)&7)) + (d2&1)
//     write quad = (c^mu)&7 distinct; read random (inherent)
// ============================================================================

__device__ __forceinline__ void h16f2(float2 v[16]) {
#pragma unroll
    for (int b = 1; b < 16; b <<= 1) {
#pragma unroll
        for (int r = 0; r < 16; ++r) {
            if ((r & b) == 0) {
                const float2 u = v[r];
                const float2 w = v[r | b];
                v[r].x     = u.x + w.x;  v[r].y     = u.y + w.y;
                v[r | b].x = u.x - w.x;  v[r | b].y = u.y - w.y;
            }
        }
    }
}

// Per-launch precompute: gaddr2[k] = W-layout float2-index of element perm[k];
// gg = diag_g/64, ss = diag_s/64.
__global__ void ff_setup(const float* __restrict__ diag_s,
                         const float* __restrict__ diag_g,
                         const int*   __restrict__ perm,
                         int*   __restrict__ gaddr2,
                         float* __restrict__ gg,
                         float* __restrict__ ss) {
    const int k   = blockIdx.x * 256 + threadIdx.x;
    const int pe  = perm[k];
    const int d2p = pe >> 8, d1p = (pe >> 4) & 15, d0p = pe & 15;
    gaddr2[k] = 512 * (d2p >> 1) + 32 * d1p + 2 * (d0p ^ ((d2p >> 1) & 7)) + (d2p & 1);
    gg[k] = diag_g[k] * S64;
    ss[k] = diag_s[k] * S64;
}

__global__ __launch_bounds__(256) void fastfood_f2_kernel(
    const float* __restrict__ x,
    const float* __restrict__ diag_b,
    const int*   __restrict__ gaddr2,
    const float* __restrict__ gg,
    const float* __restrict__ ss,
    float* __restrict__ out)
{
    __shared__ __align__(16) float2 lds2[FF_N];   // 32 KB
    const int t = threadIdx.x;
    const int T = t >> 4, c = t & 15;
    const int h = c >> 3;                         // P-layout pack-swap bit
    const size_t rowA = (size_t)blockIdx.x * 2;
    const float* __restrict__ xA   = x   + rowA * FF_N;
    const float* __restrict__ xB   = xA  + FF_N;
    float* __restrict__       outA = out + rowA * FF_N;
    float* __restrict__       outB = outA + FF_N;

    float2 v2[16];

    // ===== P1: load both rows * diag_b (float4, coalesced); h16(d0); A-write =====
    {
        const float4* __restrict__ xa4 = (const float4*)(xA + 16 * t);
        const float4* __restrict__ xb4 = (const float4*)(xB + 16 * t);
        const float4* __restrict__ b4  = (const float4*)(diag_b + 16 * t);
#pragma unroll
        for (int q = 0; q < 4; ++q) {
            const float4 bv = b4[q];
            const float4 av = xa4[q];
            const float4 wv = xb4[q];
            v2[4 * q + 0] = make_float2(av.x * bv.x, wv.x * bv.x);
            v2[4 * q + 1] = make_float2(av.y * bv.y, wv.y * bv.y);
            v2[4 * q + 2] = make_float2(av.z * bv.z, wv.z * bv.z);
            v2[4 * q + 3] = make_float2(av.w * bv.w, wv.w * bv.w);
        }
        h16f2(v2);
        // aA(d1=c, d2=T, d0=2m|2m+1): base = 256c + 16T + 2*(m^(c&7))
#pragma unroll
        for (int m = 0; m < 8; ++m) {
            const int p = 256 * c + 16 * T + 2 * (m ^ (c & 7));
            *(float4*)&lds2[p] = make_float4(v2[2 * m].x, v2[2 * m].y,
                                             v2[2 * m + 1].x, v2[2 * m + 1].y);
        }
    }
    __syncthreads();

    // ===== P2: A-read all d1 (b64); h16(d1); P-write =====
#pragma unroll
    for (int j = 0; j < 16; ++j)
        v2[j] = lds2[256 * j + 16 * T + 2 * ((c >> 1) ^ (j & 7)) + (c & 1)];
    h16f2(v2);
    __syncthreads();
    // aP(d2=T, d1=2m+?, d0=c): base = 256T + 32m + 2c; slot0 holds d1=2m+h
#pragma unroll
    for (int m = 0; m < 8; ++m) {
        const int p = 256 * T + 32 * m + 2 * c;
        const float2 lo = h ? v2[2 * m + 1] : v2[2 * m];
        const float2 hi = h ? v2[2 * m]     : v2[2 * m + 1];
        *(float4*)&lds2[p] = make_float4(lo.x, lo.y, hi.x, hi.y);
    }
    __syncthreads();

    // ===== P3: P-read all d2 (b64); h16(d2) -> FWHT1 done; W-write =====
#pragma unroll
    for (int j = 0; j < 16; ++j)
        v2[j] = lds2[256 * j + 32 * (T >> 1) + 2 * c + ((T & 1) ^ h)];
    h16f2(v2);
    __syncthreads();
    // aW(d2=2mu|2mu+1, d1=T, d0=c): base = 512mu + 32T + 2*(c^(mu&7))
#pragma unroll
    for (int mu = 0; mu < 8; ++mu) {
        const int p = 512 * mu + 32 * T + 2 * (c ^ (mu & 7));
        *(float4*)&lds2[p] = make_float4(v2[2 * mu].x, v2[2 * mu].y,
                                         v2[2 * mu + 1].x, v2[2 * mu + 1].y);
    }
    __syncthreads();

    // ===== P4: precomputed gather (b64, both rows at once) * gg; h16(d0') =====
    {
        const int4*   __restrict__ ga4 = (const int4*)(gaddr2 + 16 * t);
        const float4* __restrict__ gg4 = (const float4*)(gg + 16 * t);
#pragma unroll
        for (int q = 0; q < 4; ++q) {
            const int4   pa = ga4[q];
            const float4 gv = gg4[q];
            float2 a0 = lds2[pa.x], a1 = lds2[pa.y], a2 = lds2[pa.z], a3 = lds2[pa.w];
            v2[4 * q + 0] = make_float2(a0.x * gv.x, a0.y * gv.x);
            v2[4 * q + 1] = make_float2(a1.x * gv.y, a1.y * gv.y);
            v2[4 * q + 2] = make_float2(a2.x * gv.z, a2.y * gv.z);
            v2[4 * q + 3] = make_float2(a3.x * gv.w, a3.y * gv.w);
        }
        h16f2(v2);
    }
    __syncthreads();
    // ===== P4w: A-write (identical to P1w) =====
#pragma unroll
    for (int m = 0; m < 8; ++m) {
        const int p = 256 * c + 16 * T + 2 * (m ^ (c & 7));
        *(float4*)&lds2[p] = make_float4(v2[2 * m].x, v2[2 * m].y,
                                         v2[2 * m + 1].x, v2[2 * m + 1].y);
    }
    __syncthreads();

    // ===== P5: A-read; h16(d1'); P-write =====
#pragma unroll
    for (int j = 0; j < 16; ++j)
        v2[j] = lds2[256 * j + 16 * T + 2 * ((c >> 1) ^ (j & 7)) + (c & 1)];
    h16f2(v2);
    __syncthreads();
#pragma unroll
    for (int m = 0; m < 8; ++m) {
        const int p = 256 * T + 32 * m + 2 * c;
        const float2 lo = h ? v2[2 * m + 1] : v2[2 * m];
        const float2 hi = h ? v2[2 * m]     : v2[2 * m + 1];
        *(float4*)&lds2[p] = make_float4(lo.x, lo.y, hi.x, hi.y);
    }
    __syncthreads();

    // ===== P6: P-read; h16(d2'); DENSE store out[256j + t] * ss =====
#pragma unroll
    for (int j = 0; j < 16; ++j)
        v2[j] = lds2[256 * j + 32 * (T >> 1) + 2 * c + ((T & 1) ^ h)];
    h16f2(v2);
#pragma unroll
    for (int j = 0; j < 16; ++j) {
        const int e = 256 * j + t;
        const float s = ss[e];
        outA[e] = v2[j].x * s;
        outB[e] = v2[j].y * s;
    }
}

extern "C" void kernel_launch(void* const* d_in, const int* in_sizes, int n_in,
                              void* d_out, int out_size, void* d_ws, size_t ws_size,
                              hipStream_t stream) {
    const float* x      = (const float*)d_in[0];
    const float* diag_s = (const float*)d_in[1];
    const float* diag_g = (const float*)d_in[2];
    const float* diag_b = (const float*)d_in[3];
    const int*   perm   = (const int*)d_in[4];
    float* out = (float*)d_out;

    int*   gaddr2 = (int*)d_ws;
    float* gg     = (float*)d_ws + FF_N;
    float* ss     = (float*)d_ws + 2 * FF_N;

    ff_setup<<<FF_N / 256, 256, 0, stream>>>(diag_s, diag_g, perm, gaddr2, gg, ss);

    const int batch = in_sizes[0] / FF_N;   // 16384 rows
    fastfood_f2_kernel<<<batch / 2, 256, 0, stream>>>(x, diag_b, gaddr2, gg, ss, out);
}

// Round 12
// 94.257 us; speedup vs baseline: 1.2486x; 1.2486x over previous
//
#include <hip/hip_runtime.h>

#define FF_N 4096
#define S64  0.015625f   // 1/64 per FWHT (total 1/4096)

typedef float v2f __attribute__((ext_vector_type(2)));

// Packed fp32 (VOP3P) — both rows' butterfly op in one instruction.
__device__ __forceinline__ v2f pk_add(v2f a, v2f b) {
    v2f d; asm("v_pk_add_f32 %0, %1, %2" : "=v"(d) : "v"(a), "v"(b)); return d;
}
__device__ __forceinline__ v2f pk_sub(v2f a, v2f b) {
    v2f d; asm("v_pk_add_f32 %0, %1, %2 neg_lo:[0,1] neg_hi:[0,1]"
               : "=v"(d) : "v"(a), "v"(b)); return d;
}

__device__ __forceinline__ void h16p(v2f v[16]) {
#pragma unroll
    for (int b = 1; b < 16; b <<= 1) {
#pragma unroll
        for (int r = 0; r < 16; ++r) {
            if ((r & b) == 0) {
                const v2f u = v[r], w = v[r | b];
                v[r]     = pk_add(u, w);
                v[r | b] = pk_sub(u, w);
            }
        }
    }
}

// Per-launch precompute: gaddr2[k] = W-layout float2-index of element perm[k];
// gg = diag_g/64, ss = diag_s/64.  (Layouts identical to R11 — verified.)
__global__ void ff_setup(const float* __restrict__ diag_s,
                         const float* __restrict__ diag_g,
                         const int*   __restrict__ perm,
                         int*   __restrict__ gaddr2,
                         float* __restrict__ gg,
                         float* __restrict__ ss) {
    const int k   = blockIdx.x * 256 + threadIdx.x;
    const int pe  = perm[k];
    const int d2p = pe >> 8, d1p = (pe >> 4) & 15, d0p = pe & 15;
    gaddr2[k] = 512 * (d2p >> 1) + 32 * d1p + 2 * (d0p ^ ((d2p >> 1) & 7)) + (d2p & 1);
    gg[k] = diag_g[k] * S64;
    ss[k] = diag_s[k] * S64;
}

// R11 structure: 2 rows/block packed as v2f, radix-16 digit rotation,
// 5 conflict-free LDS junctions (A/P/W layouts, R8-validated rigid-group
// model). New in R12: packed butterflies + nontemporal output stores.
__global__ __launch_bounds__(256) void fastfood_pk_kernel(
    const float* __restrict__ x,
    const float* __restrict__ diag_b,
    const int*   __restrict__ gaddr2,
    const float* __restrict__ gg,
    const float* __restrict__ ss,
    float* __restrict__ out)
{
    __shared__ __align__(16) v2f lds2[FF_N];   // 32 KB
    const int t = threadIdx.x;
    const int T = t >> 4, c = t & 15;
    const int h = c >> 3;                      // P-layout pack-swap bit
    const size_t rowA = (size_t)blockIdx.x * 2;
    const float* __restrict__ xA   = x   + rowA * FF_N;
    const float* __restrict__ xB   = xA  + FF_N;
    float* __restrict__       outA = out + rowA * FF_N;
    float* __restrict__       outB = outA + FF_N;

    v2f v2[16];

    // ===== P1: load both rows * diag_b (float4, coalesced); h16(d0); A-write =====
    {
        const float4* __restrict__ xa4 = (const float4*)(xA + 16 * t);
        const float4* __restrict__ xb4 = (const float4*)(xB + 16 * t);
        const float4* __restrict__ b4  = (const float4*)(diag_b + 16 * t);
#pragma unroll
        for (int q = 0; q < 4; ++q) {
            const float4 bv = b4[q];
            const float4 av = xa4[q];
            const float4 wv = xb4[q];
            v2[4 * q + 0][0] = av.x * bv.x;  v2[4 * q + 0][1] = wv.x * bv.x;
            v2[4 * q + 1][0] = av.y * bv.y;  v2[4 * q + 1][1] = wv.y * bv.y;
            v2[4 * q + 2][0] = av.z * bv.z;  v2[4 * q + 2][1] = wv.z * bv.z;
            v2[4 * q + 3][0] = av.w * bv.w;  v2[4 * q + 3][1] = wv.w * bv.w;
        }
        h16p(v2);
        // aA(d1=c, d2=T, d0=2m|2m+1): base = 256c + 16T + 2*(m^(c&7))
#pragma unroll
        for (int m = 0; m < 8; ++m) {
            const int p = 256 * c + 16 * T + 2 * (m ^ (c & 7));
            *(float4*)&lds2[p] = make_float4(v2[2 * m][0], v2[2 * m][1],
                                             v2[2 * m + 1][0], v2[2 * m + 1][1]);
        }
    }
    __syncthreads();

    // ===== P2: A-read all d1 (b64); h16(d1); P-write =====
#pragma unroll
    for (int j = 0; j < 16; ++j)
        v2[j] = lds2[256 * j + 16 * T + 2 * ((c >> 1) ^ (j & 7)) + (c & 1)];
    h16p(v2);
    __syncthreads();
    // aP(d2=T, d1=2m+?, d0=c): base = 256T + 32m + 2c; slot0 holds d1=2m+h
#pragma unroll
    for (int m = 0; m < 8; ++m) {
        const int p = 256 * T + 32 * m + 2 * c;
        const v2f lo = h ? v2[2 * m + 1] : v2[2 * m];
        const v2f hi = h ? v2[2 * m]     : v2[2 * m + 1];
        *(float4*)&lds2[p] = make_float4(lo[0], lo[1], hi[0], hi[1]);
    }
    __syncthreads();

    // ===== P3: P-read all d2 (b64); h16(d2) -> FWHT1 done; W-write =====
#pragma unroll
    for (int j = 0; j < 16; ++j)
        v2[j] = lds2[256 * j + 32 * (T >> 1) + 2 * c + ((T & 1) ^ h)];
    h16p(v2);
    __syncthreads();
    // aW(d2=2mu|2mu+1, d1=T, d0=c): base = 512mu + 32T + 2*(c^(mu&7))
#pragma unroll
    for (int mu = 0; mu < 8; ++mu) {
        const int p = 512 * mu + 32 * T + 2 * (c ^ (mu & 7));
        *(float4*)&lds2[p] = make_float4(v2[2 * mu][0], v2[2 * mu][1],
                                         v2[2 * mu + 1][0], v2[2 * mu + 1][1]);
    }
    __syncthreads();

    // ===== P4: precomputed gather (b64, both rows at once) * gg; h16(d0') =====
    {
        const int4*   __restrict__ ga4 = (const int4*)(gaddr2 + 16 * t);
        const float4* __restrict__ gg4 = (const float4*)(gg + 16 * t);
#pragma unroll
        for (int q = 0; q < 4; ++q) {
            const int4   pa = ga4[q];
            const float4 gv = gg4[q];
            const v2f a0 = lds2[pa.x], a1 = lds2[pa.y];
            const v2f a2 = lds2[pa.z], a3 = lds2[pa.w];
            v2[4 * q + 0][0] = a0[0] * gv.x;  v2[4 * q + 0][1] = a0[1] * gv.x;
            v2[4 * q + 1][0] = a1[0] * gv.y;  v2[4 * q + 1][1] = a1[1] * gv.y;
            v2[4 * q + 2][0] = a2[0] * gv.z;  v2[4 * q + 2][1] = a2[1] * gv.z;
            v2[4 * q + 3][0] = a3[0] * gv.w;  v2[4 * q + 3][1] = a3[1] * gv.w;
        }
        h16p(v2);
    }
    __syncthreads();
    // ===== P4w: A-write (identical to P1w) =====
#pragma unroll
    for (int m = 0; m < 8; ++m) {
        const int p = 256 * c + 16 * T + 2 * (m ^ (c & 7));
        *(float4*)&lds2[p] = make_float4(v2[2 * m][0], v2[2 * m][1],
                                         v2[2 * m + 1][0], v2[2 * m + 1][1]);
    }
    __syncthreads();

    // ===== P5: A-read; h16(d1'); P-write =====
#pragma unroll
    for (int j = 0; j < 16; ++j)
        v2[j] = lds2[256 * j + 16 * T + 2 * ((c >> 1) ^ (j & 7)) + (c & 1)];
    h16p(v2);
    __syncthreads();
#pragma unroll
    for (int m = 0; m < 8; ++m) {
        const int p = 256 * T + 32 * m + 2 * c;
        const v2f lo = h ? v2[2 * m + 1] : v2[2 * m];
        const v2f hi = h ? v2[2 * m]     : v2[2 * m + 1];
        *(float4*)&lds2[p] = make_float4(lo[0], lo[1], hi[0], hi[1]);
    }
    __syncthreads();

    // ===== P6: P-read; h16(d2'); DENSE nontemporal store out[256j+t] * ss =====
#pragma unroll
    for (int j = 0; j < 16; ++j)
        v2[j] = lds2[256 * j + 32 * (T >> 1) + 2 * c + ((T & 1) ^ h)];
    h16p(v2);
#pragma unroll
    for (int j = 0; j < 16; ++j) {
        const int e = 256 * j + t;
        const float s = ss[e];
        __builtin_nontemporal_store(v2[j][0] * s, &outA[e]);
        __builtin_nontemporal_store(v2[j][1] * s, &outB[e]);
    }
}

extern "C" void kernel_launch(void* const* d_in, const int* in_sizes, int n_in,
                              void* d_out, int out_size, void* d_ws, size_t ws_size,
                              hipStream_t stream) {
    const float* x      = (const float*)d_in[0];
    const float* diag_s = (const float*)d_in[1];
    const float* diag_g = (const float*)d_in[2];
    const float* diag_b = (const float*)d_in[3];
    const int*   perm   = (const int*)d_in[4];
    float* out = (float*)d_out;

    int*   gaddr2 = (int*)d_ws;
    float* gg     = (float*)d_ws + FF_N;
    float* ss     = (float*)d_ws + 2 * FF_N;

    ff_setup<<<FF_N / 256, 256, 0, stream>>>(diag_s, diag_g, perm, gaddr2, gg, ss);

    const int batch = in_sizes[0] / FF_N;   // 16384 rows
    fastfood_pk_kernel<<<batch / 2, 256, 0, stream>>>(x, diag_b, gaddr2, gg, ss, out);
}